// Round 12
// baseline (121.267 us; speedup 1.0000x reference)
//
#include <hip/hip_runtime.h>
#include <type_traits>

// PopulationCoding, round 12.
//  r11 ledger: total 121 = fill 40.5 + gaps ~5 + gemm ~40 + epi ~35.
//  K1 (single variable this round): 8rx8c fragment -> LDS bytes/FMA
//      4*(1/8+1/8)=1.0, pipe floor 20.5us. TM=TN=128, 256 thr, TK=32
//      single-buffered (33KB -> 4 blk/CU x 4 waves = 16 waves/CU),
//      nsplit=8 -> 1024 blocks. B-fragment = cols [4dl,+4)u[64+4dl,+4):
//      Bs reads 2-way aliased (free); As reads quad-broadcast (free).
//      launch_bounds(256,2) -> VGPR cap ~128 (observed arg4->64 mapping).
//  K2: r11 epi unchanged except 8-slice gather.
// B=1024, IN=512, D=256, P=8, T=32. Output [1024,256] fp32.

constexpr int IN_DIM  = 512;
constexpr int D_DIM   = 256;
constexpr int NTOT    = 2048;   // D*P
constexpr int T_STEPS = 32;

constexpr int TM = 128;
constexpr int TN = 128;
constexpr int TK = 32;
constexpr int NSPLIT = 8;
constexpr int KSPLIT = IN_DIM / NSPLIT;   // 64 -> 2 chunks of 32

// ---------------------------------------------------------------- K1: GEMM
__global__ __launch_bounds__(256, 2)
void popcode_gemm(const float* __restrict__ x,
                  const float* __restrict__ Wp,
                  float* __restrict__ ws)    // [8][1024][2048] partial I
{
    // As [k][row] stride 132 (16B-aligned row-quads): reads are 4-quad
    // broadcast, conflict-free. Bs [k][col] stride 128: reads at 4dl and
    // 64+4dl are 2-way bank-aliased (free). 33 KB -> 4 blocks/CU.
    __shared__ float As[TK][TM + 4];
    __shared__ float Bs[TK][TN];

    const int tid = threadIdx.x;   // 0..255
    const int b0  = blockIdx.x * TM;
    const int c0  = blockIdx.y * TN;
    const int k0  = blockIdx.z * KSPLIT;
    const int rg  = tid >> 4;      // 0..15
    const int dl  = tid & 15;      // 0..15
    const int r8  = rg * 8;        // first of this thread's 8 rows

    float acc[8][8];
#pragma unroll
    for (int i = 0; i < 8; ++i)
#pragma unroll
        for (int j = 0; j < 8; ++j) acc[i][j] = 0.f;

    for (int kc = k0; kc < k0 + KSPLIT; kc += TK) {
        // stage A: 128 rows x 32 k (4096 floats), 256 thr x 4 float4,
        // transpose into As
#pragma unroll
        for (int i = 0; i < 4; ++i) {
            const int f   = tid + 256 * i;       // 0..1023
            const int row = f >> 3;              // 0..127
            const int c4  = (f & 7) * 4;         // 0..28
            const float4 v =
                *reinterpret_cast<const float4*>(x + (b0 + row) * IN_DIM + kc + c4);
            As[c4 + 0][row] = v.x;
            As[c4 + 1][row] = v.y;
            As[c4 + 2][row] = v.z;
            As[c4 + 3][row] = v.w;
        }
        // stage B: 32 rows x 128 cols, row-major b128 writes
#pragma unroll
        for (int i = 0; i < 4; ++i) {
            const int f  = tid + 256 * i;        // 0..1023
            const int r  = f >> 5;               // 0..31
            const int c4 = (f & 31) * 4;         // 0..124
            *reinterpret_cast<float4*>(&Bs[r][c4]) =
                *reinterpret_cast<const float4*>(Wp + (kc + r) * NTOT + c0 + c4);
        }
        __syncthreads();

#pragma unroll 8
        for (int k = 0; k < TK; ++k) {
            const float4 a0 = *reinterpret_cast<const float4*>(&As[k][r8]);
            const float4 a1 = *reinterpret_cast<const float4*>(&As[k][r8 + 4]);
            const float4 u0 = *reinterpret_cast<const float4*>(&Bs[k][4 * dl]);
            const float4 u1 = *reinterpret_cast<const float4*>(&Bs[k][64 + 4 * dl]);
            const float ar[8] = {a0.x, a0.y, a0.z, a0.w, a1.x, a1.y, a1.z, a1.w};
#pragma unroll
            for (int r = 0; r < 8; ++r) {
                acc[r][0] += ar[r] * u0.x;  acc[r][1] += ar[r] * u0.y;
                acc[r][2] += ar[r] * u0.z;  acc[r][3] += ar[r] * u0.w;
                acc[r][4] += ar[r] * u1.x;  acc[r][5] += ar[r] * u1.y;
                acc[r][6] += ar[r] * u1.z;  acc[r][7] += ar[r] * u1.w;
            }
        }
        __syncthreads();
    }

    // write partial I: 8 rows, cols c0+4dl..+3 and c0+64+4dl..+3
    float* dst = ws + (size_t)blockIdx.z * 1024 * NTOT;
#pragma unroll
    for (int bi = 0; bi < 8; ++bi) {
        float* p = dst + (size_t)(b0 + r8 + bi) * NTOT + c0;
        *reinterpret_cast<float4*>(p + 4 * dl) =
            {acc[bi][0], acc[bi][1], acc[bi][2], acc[bi][3]};
        *reinterpret_cast<float4*>(p + 64 + 4 * dl) =
            {acc[bi][4], acc[bi][5], acc[bi][6], acc[bi][7]};
    }
}

// ------------------------------------------------------------ K2: epilogue
// 2 threads per neuron: waves (0,1) and (2,3) are partner pairs (thread tid
// partners tid^64). h = wave&1 selects p-half (LIF) and t-half (conv).
__global__ __launch_bounds__(256)
void popcode_epi(const float* __restrict__ ws,
                 const float* __restrict__ bp,
                 const float* __restrict__ thrs,
                 const float* __restrict__ rateW,
                 const float* __restrict__ rateB,
                 const float* __restrict__ c1w,
                 const float* __restrict__ c1b,
                 const float* __restrict__ c2w,
                 const float* __restrict__ c2b,
                 const float* __restrict__ fus,
                 float* __restrict__ out)
{
    __shared__ float lut[3][256][4];     // 12 KB (bias folded into tap 1)
    __shared__ float rlut[256];          // 1 KB
    __shared__ float wlds[96];
    __shared__ uint4 exch[256];          // 4 KB nibble exchange / partial sums

    const int tid = threadIdx.x;
    const int wv  = tid >> 6;
    const int h   = wv & 1;                         // wave-uniform
    const int nl  = ((wv >> 1) << 6) | (tid & 63);  // 0..127
    const int n   = blockIdx.x * 128 + nl;
    const int b   = n >> 8;
    const int d   = n & 255;

    // ---- build LUTs (once per block) ----
    if (tid < 96) wlds[tid] = c1w[tid];
    {
        float rv = 0.f;
#pragma unroll
        for (int p = 0; p < 8; ++p)
            rv += (float)((tid >> p) & 1) * rateW[p];
        rlut[tid] = rv;
    }
    __syncthreads();
#pragma unroll
    for (int i = 0; i < 12; ++i) {
        const int e    = 256 * i + tid;      // 0..3071
        const int k    = e >> 10;
        const int byte = (e >> 2) & 255;
        const int c    = e & 3;
        float v = (k == 1) ? c1b[c] : 0.f;   // fold conv1 bias into tap 1
#pragma unroll
        for (int p = 0; p < 8; ++p)
            v = fmaf((float)((byte >> p) & 1), wlds[(c * 8 + p) * 3 + k], v);
        (&lut[0][0][0])[e] = v;
    }

    // ---- uniform scalars ----
    float w2c[4];
#pragma unroll
    for (int c = 0; c < 4; ++c) w2c[c] = c2w[c];
    const float rb_ = rateB[0];
    const float bb2 = c2b[0];
    const float f0 = fus[0], f1 = fus[1];
    const float fm = fmaxf(f0, f1);
    const float e0 = __expf(f0 - fm), e1 = __expf(f1 - fm);
    const float inv = 1.f / (e0 + e1);
    const float fw0 = e0 * inv, fw1 = e1 * inv;

    // ---- gather I for this thread's 4 p's: sum the 8 k-slices ----
    const size_t base  = (size_t)b * NTOT + d * 8 + h * 4;
    const size_t slice = (size_t)1024 * NTOT;
    float4 iv = *reinterpret_cast<const float4*>(ws + base);
#pragma unroll
    for (int s = 1; s < NSPLIT; ++s) {
        const float4 q = *reinterpret_cast<const float4*>(ws + s * slice + base);
        iv.x += q.x; iv.y += q.y; iv.z += q.z; iv.w += q.w;
    }
    const float4 bpv = *reinterpret_cast<const float4*>(bp + d * 8 + h * 4);
    const float4 tv  = *reinterpret_cast<const float4*>(thrs + h * 4);
    float Iv[4]  = {iv.x + bpv.x, iv.y + bpv.y, iv.z + bpv.z, iv.w + bpv.w};
    float thr[4] = {tv.x, tv.y, tv.z, tv.w};
    float Imt[4], mem[4];
    bool  spk[4];
#pragma unroll
    for (int p = 0; p < 4; ++p) {
        Imt[p] = Iv[p] - thr[p];
        mem[p] = 0.f;
        spk[p] = false;
    }

    // ---- LIF for 4 p's, packing a nibble per t (8 t per u32) ----
    unsigned nib[4] = {0u, 0u, 0u, 0u};
#pragma unroll
    for (int t = 0; t < T_STEPS; ++t) {
        unsigned nb = 0u;
#pragma unroll
        for (int p = 0; p < 4; ++p) {
            mem[p] = 0.95f * mem[p] + (spk[p] ? Imt[p] : Iv[p]);
            spk[p] = mem[p] > thr[p];
            nb |= spk[p] ? (1u << p) : 0u;
        }
        nib[t >> 3] |= nb << (4 * (t & 7));
    }

    // ---- exchange nibbles with the partner thread (other wave) ----
    __syncthreads();   // lut build + exch ready
    exch[tid] = uint4{nib[0], nib[1], nib[2], nib[3]};
    __syncthreads();
    const uint4 pr = exch[tid ^ 64];
    const unsigned prn[4] = {pr.x, pr.y, pr.z, pr.w};
    unsigned lo[4], hi[4];
#pragma unroll
    for (int w = 0; w < 4; ++w) {
        lo[w] = h ? prn[w] : nib[w];   // p0..3 half
        hi[w] = h ? nib[w] : prn[w];   // p4..7 half
    }

    // ---- conv + rate over this thread's half of the t-range ----
    auto getbyte = [&](int t) -> unsigned {
        const int w = t >> 3, s = 4 * (t & 7);
        return ((lo[w] >> s) & 15u) | (((hi[w] >> s) & 15u) << 4);
    };
    const float* lutf = &lut[0][0][0];
    float tacc = 0.f, rsum = 0.f;

    auto conv_half = [&](auto T0C) {
        constexpr int T0 = T0C.value;
        unsigned bprev = (T0 == 0) ? 0u : getbyte(T0 - 1);
        unsigned bcur  = getbyte(T0);
#pragma unroll
        for (int i = 0; i < 16; ++i) {
            const int t = T0 + i;
            const unsigned bnext = (t < 31) ? getbyte(t + 1) : 0u;
            const float4 fa = *reinterpret_cast<const float4*>(lutf + bprev * 4);
            const float4 fb = *reinterpret_cast<const float4*>(lutf + 1024 + bcur * 4);
            const float4 fc = *reinterpret_cast<const float4*>(lutf + 2048 + bnext * 4);
            rsum += rlut[bcur];
            const float h0_ = (fa.x + fb.x) + fc.x;
            const float h1_ = (fa.y + fb.y) + fc.y;
            const float h2_ = (fa.z + fb.z) + fc.z;
            const float h3_ = (fa.w + fb.w) + fc.w;
            tacc = fmaf(fmaxf(h0_, 0.f), w2c[0], tacc);
            tacc = fmaf(fmaxf(h1_, 0.f), w2c[1], tacc);
            tacc = fmaf(fmaxf(h2_, 0.f), w2c[2], tacc);
            tacc = fmaf(fmaxf(h3_, 0.f), w2c[3], tacc);
            bprev = bcur;
            bcur  = bnext;
        }
    };
    if (h == 0) conv_half(std::integral_constant<int, 0>{});
    else        conv_half(std::integral_constant<int, 16>{});

    // ---- combine partner partial sums, write ----
    __syncthreads();   // all exch reads done
    float2* e2 = reinterpret_cast<float2*>(exch);
    e2[tid] = float2{rsum, tacc};
    __syncthreads();
    const float2 q = e2[tid ^ 64];
    rsum += q.x;
    tacc += q.y;

    if (h == 0) {
        const float rdec = rsum * (1.f / 32.f) + rb_;
        const float temp = tacc * (1.f / 32.f) + bb2;
        out[b * D_DIM + d] = fw0 * rdec + fw1 * temp;
    }
}

extern "C" void kernel_launch(void* const* d_in, const int* in_sizes, int n_in,
                              void* d_out, int out_size, void* d_ws, size_t ws_size,
                              hipStream_t stream) {
    const float* x     = (const float*)d_in[0];
    const float* Wp    = (const float*)d_in[1];
    const float* bp    = (const float*)d_in[2];
    const float* thrs  = (const float*)d_in[3];
    const float* rateW = (const float*)d_in[4];
    const float* rateB = (const float*)d_in[5];
    const float* c1w   = (const float*)d_in[6];
    const float* c1b   = (const float*)d_in[7];
    const float* c2w   = (const float*)d_in[8];
    const float* c2b   = (const float*)d_in[9];
    const float* fus   = (const float*)d_in[10];
    float* out = (float*)d_out;
    float* ws  = (float*)d_ws;

    dim3 g1(1024 / TM, NTOT / TN, NSPLIT);   // 8 x 16 x 8 = 1024 blocks
    popcode_gemm<<<g1, dim3(256), 0, stream>>>(x, Wp, ws);

    popcode_epi<<<dim3(2048), dim3(256), 0, stream>>>(
        ws, bp, thrs, rateW, rateB, c1w, c1b, c2w, c2b, fus, out);
}